// Round 8
// baseline (884.933 us; speedup 1.0000x reference)
//
#include <hip/hip_runtime.h>
#include <hip/hip_fp16.h>
#include <cstdint>

// MessagePassing — MFMA edge-MLP (sorted output) + LDS-staged streaming aggregation.
// N=20000, E=320000. CS=64, CV=32, CM=96, WN=192, FCH=64.

#define CS 64
#define CV 32
#define CM 96
#define WN 192
#define FCH 64
#define WPAD 72     // padded K-stride (halfs) for LDS weight tiles
#define CHUNK 32    // edges staged per LDS batch in agg_post

using f16x8 = __attribute__((ext_vector_type(8))) _Float16;
using f32x4 = __attribute__((ext_vector_type(4))) float;

__device__ __forceinline__ float siluf(float x){ return x / (1.f + __expf(-x)); }

constexpr float INV8       = 0.125f;
constexpr float INV_SQRT32 = 0.17677669529663687f;
constexpr float INV_SQRT96 = 0.10206207261596575f;
constexpr float INV_SQRT3  = 0.5773502691896258f;

// ---------------- histogram of edge_dst ----------------
__global__ void hist_kernel(const int* __restrict__ edst, int* __restrict__ cnt, int E){
    int e = blockIdx.x*blockDim.x + threadIdx.x;
    if (e < E) atomicAdd(&cnt[edst[e]], 1);
}

// ---------------- single-block exclusive scan ----------------
__global__ void scan_kernel(const int* __restrict__ cnt, int* __restrict__ row_start,
                            int* __restrict__ cursor, int n, int E){
    __shared__ int part[1024];
    const int t = threadIdx.x;
    const int C = (n + 1023) / 1024;
    int local[32];
    int base = t*C;
    int s = 0;
    for (int j = 0; j < C && j < 32; ++j){
        int idx = base + j;
        int v = (idx < n) ? cnt[idx] : 0;
        local[j] = s; s += v;
    }
    part[t] = s;
    __syncthreads();
    for (int off = 1; off < 1024; off <<= 1){
        int v = (t >= off) ? part[t-off] : 0;
        __syncthreads();
        part[t] += v;
        __syncthreads();
    }
    int pre = (t == 0) ? 0 : part[t-1];
    for (int j = 0; j < C && j < 32; ++j){
        int idx = base + j;
        if (idx < n){ int rs = pre + local[j]; row_start[idx] = rs; cursor[idx] = rs; }
    }
    if (t == 0) row_start[n] = E;
}

// ---------------- scatter: perm + sorted eattr/esrc sidecars ----------------
__global__ void scatter_kernel(const int* __restrict__ edst, const int* __restrict__ esrc,
                               const float4* __restrict__ eattr,
                               int* __restrict__ cursor, int* __restrict__ perm,
                               float4* __restrict__ eattr_s, int* __restrict__ esrc_s, int E){
    int e = blockIdx.x*blockDim.x + threadIdx.x;
    if (e < E){
        int p = atomicAdd(&cursor[edst[e]], 1);
        perm[p] = e; eattr_s[p] = eattr[e]; esrc_s[p] = esrc[e];
    }
}

__global__ void isd_kernel(const int* __restrict__ cnt, float* __restrict__ isd, int n){
    int i = blockIdx.x*blockDim.x + threadIdx.x;
    if (i < n) isd[i] = rsqrtf((float)cnt[i]);
}

// ---------------- weight prep: f32 -> f16, transpose, pad, fold 1/8 ----------------
__global__ void wprep(const float* __restrict__ Wfa1, const float* __restrict__ Wfb1,
                      const float* __restrict__ Wfa2, const float* __restrict__ Wfb2,
                      __half* __restrict__ Wc1, __half* __restrict__ Wc2){
    int t = blockIdx.x*blockDim.x + threadIdx.x;
    if (t < 64*WPAD){
        int c = t / WPAD, k = t - c*WPAD;
        float v1 = (k < 64) ? Wfa1[k*64 + c]*INV8 : 0.f;
        float v2 = (k < 64) ? Wfa2[k*64 + c]*INV8 : 0.f;
        Wc1[t] = __float2half(v1); Wc2[t] = __float2half(v2);
    } else if (t < 64*WPAD + 192*WPAD){
        int q = t - 64*WPAD; int o = q / WPAD, k = q - o*WPAD;
        float v1 = (k < 64) ? Wfb1[k*192 + o]*INV8 : 0.f;
        float v2 = (k < 64) ? Wfb2[k*192 + o]*INV8 : 0.f;
        Wc1[t] = __float2half(v1); Wc2[t] = __float2half(v2);
    }
}

// ---------------- node pre-transform ----------------
template<int OS>
__global__ void node_pre(const float* __restrict__ s, int ss,
                         const float* __restrict__ v, int vs,
                         const float* __restrict__ attr,
                         const float* __restrict__ Wl1s, const float* __restrict__ Wscs,
                         const float* __restrict__ Wl1v, const float* __restrict__ Wscv,
                         float* __restrict__ f_s, float* __restrict__ sc_s,
                         float* __restrict__ f_v, float* __restrict__ sc_v, int n_nodes)
{
    constexpr int TOT = 64 + OS + 96 + 96;
    int t = blockIdx.x*blockDim.x + threadIdx.x;
    if (t >= n_nodes*TOT) return;
    int n = t / TOT, r = t - n*TOT;
    float a = attr[n];
    const float* srow = s + (size_t)n*ss;
    const float* vrow = v + (size_t)n*vs;

    if (r < 64 + OS){
        float acc = 0.f;
        if (r < 64){
            const float* col = Wl1s + r;
            #pragma unroll 8
            for (int k = 0; k < 64; ++k) acc += srow[k]*col[k*64];
            f_s[(size_t)n*64 + r] = acc * a * INV8;
        } else {
            int j = r - 64;
            const float* col = Wscs + j;
            #pragma unroll 8
            for (int k = 0; k < 64; ++k) acc += srow[k]*col[k*OS];
            sc_s[(size_t)n*OS + j] = acc * a * INV8;
        }
    } else {
        int q = r - (64 + OS);
        bool first = (q < 96);
        if (!first) q -= 96;
        int w = q/3, c = q - 3*w;
        const float* W = first ? Wl1v : Wscv;
        float acc = 0.f;
        #pragma unroll 8
        for (int u = 0; u < 32; ++u) acc += vrow[u*3 + c]*W[u*32 + w];
        float* op = (first ? f_v : sc_v) + (size_t)n*96 + q;
        *op = acc * a * INV_SQRT32;
    }
}

// ---------------- MFMA edge MLP ----------------
__global__ __launch_bounds__(256) void mlp_gemm(
    const int* __restrict__ perm, const float* __restrict__ escal,
    const __half* __restrict__ Wc, __half* __restrict__ w_s, int E)
{
    __shared__ __half lWa[64*WPAD];
    __shared__ __half lWb[192*WPAD];
    __shared__ __half hs[4][16*WPAD];

    const int tid = threadIdx.x;
    {
        const uint4* src4 = reinterpret_cast<const uint4*>(Wc);
        uint4* dA = reinterpret_cast<uint4*>(lWa);
        uint4* dB = reinterpret_cast<uint4*>(lWb);
        for (int i = tid; i < (64*WPAD)/8; i += 256) dA[i] = src4[i];
        for (int i = tid; i < (192*WPAD)/8; i += 256) dB[i] = src4[(64*WPAD)/8 + i];
    }

    const int wv = tid >> 6, l = tid & 63;
    const int lm = l & 15, kg = l >> 4;
    const int base = blockIdx.x*64 + wv*16;

    int slot = base + lm; if (slot >= E) slot = E-1;
    const int e = perm[slot];
    const float* xp = escal + (size_t)e*64 + kg*8;
    f16x8 xf0, xf1;
    {
        float4 a0 = *reinterpret_cast<const float4*>(xp);
        float4 a1 = *reinterpret_cast<const float4*>(xp + 4);
        float4 b0 = *reinterpret_cast<const float4*>(xp + 32);
        float4 b1 = *reinterpret_cast<const float4*>(xp + 36);
        xf0[0]=(_Float16)a0.x; xf0[1]=(_Float16)a0.y; xf0[2]=(_Float16)a0.z; xf0[3]=(_Float16)a0.w;
        xf0[4]=(_Float16)a1.x; xf0[5]=(_Float16)a1.y; xf0[6]=(_Float16)a1.z; xf0[7]=(_Float16)a1.w;
        xf1[0]=(_Float16)b0.x; xf1[1]=(_Float16)b0.y; xf1[2]=(_Float16)b0.z; xf1[3]=(_Float16)b0.w;
        xf1[4]=(_Float16)b1.x; xf1[5]=(_Float16)b1.y; xf1[6]=(_Float16)b1.z; xf1[7]=(_Float16)b1.w;
    }
    __syncthreads();

    #pragma unroll
    for (int nt = 0; nt < 4; ++nt){
        f16x8 wa0 = *reinterpret_cast<const f16x8*>(&lWa[(nt*16 + lm)*WPAD + kg*8]);
        f16x8 wa1 = *reinterpret_cast<const f16x8*>(&lWa[(nt*16 + lm)*WPAD + 32 + kg*8]);
        f32x4 acc = {0.f,0.f,0.f,0.f};
        acc = __builtin_amdgcn_mfma_f32_16x16x32_f16(xf0, wa0, acc, 0, 0, 0);
        acc = __builtin_amdgcn_mfma_f32_16x16x32_f16(xf1, wa1, acc, 0, 0, 0);
        #pragma unroll
        for (int r = 0; r < 4; ++r){
            hs[wv][(kg*4 + r)*WPAD + nt*16 + lm] = __float2half(siluf(acc[r]));
        }
    }
    __syncthreads();

    f16x8 ha0 = *reinterpret_cast<const f16x8*>(&hs[wv][lm*WPAD + kg*8]);
    f16x8 ha1 = *reinterpret_cast<const f16x8*>(&hs[wv][lm*WPAD + 32 + kg*8]);
    const int orow = base + kg*4;
    #pragma unroll 4
    for (int nt = 0; nt < 12; ++nt){
        f16x8 wb0 = *reinterpret_cast<const f16x8*>(&lWb[(nt*16 + lm)*WPAD + kg*8]);
        f16x8 wb1 = *reinterpret_cast<const f16x8*>(&lWb[(nt*16 + lm)*WPAD + 32 + kg*8]);
        f32x4 acc = {0.f,0.f,0.f,0.f};
        acc = __builtin_amdgcn_mfma_f32_16x16x32_f16(ha0, wb0, acc, 0, 0, 0);
        acc = __builtin_amdgcn_mfma_f32_16x16x32_f16(ha1, wb1, acc, 0, 0, 0);
        #pragma unroll
        for (int r = 0; r < 4; ++r){
            int row = orow + r;
            if (row < E) w_s[(size_t)row*WN + nt*16 + lm] = __float2half(acc[r]);
        }
    }
}

// ---------------- LDS-staged streaming aggregation + fused node post ----------------
// Roles: A t<64: asd[t] += w[t]·fs[t]·ea.x
//        C t in[64,256): j=t-64,o=j/3,c=j%3: avd[j] += w[64+o]·fs[o]·ea[1+c]
//        D t in[256,352): j2=t-256: avd[192+j2] += w[128+j2/3]·fv[j2]·ea.x
//        B t in[352,384): u=t-352: asd[64+u] += w[160+u]·(fv[3u..]·ea.yzw)/sqrt3
template<int OS, bool FINAL>
__global__ __launch_bounds__(384) void agg_post(
    const int* __restrict__ row_start, const __half* __restrict__ w_s,
    const int* __restrict__ esrc_s, const float4* __restrict__ eattr_s,
    const float* __restrict__ f_s, const float* __restrict__ f_v,
    const float* __restrict__ isd, const float* __restrict__ attr,
    const float* __restrict__ sc_s, const float* __restrict__ sc_v,
    const float* __restrict__ W2s, const float* __restrict__ W2v,
    const float* __restrict__ W3,
    float* __restrict__ out_s, float* __restrict__ out_v)
{
    const int n = blockIdx.x;
    const int t = threadIdx.x;
    const int rs = row_start[n], re = row_start[n+1];

    // role decode (fixed per thread)
    int widx, fidx, mode, eac = 0;   // 0: fs*ea[eac]; 2: fv*ea.x; 1: dot3
    if (t < 64){ widx = t; fidx = t; mode = 0; eac = 0; }
    else if (t < 256){ int j = t-64; int o = j/3; eac = 1 + (j - 3*o); widx = 64+o; fidx = o; mode = 0; }
    else if (t < 352){ int j2 = t-256; widx = 128 + j2/3; fidx = j2; mode = 2; eac = 0; }
    else { int u = t-352; widx = 160+u; fidx = 3*u; mode = 1; }

    __shared__ __align__(16) __half s_w[CHUNK*WN];      // 12 KB
    __shared__ __align__(16) float  s_f[CHUNK*160];     // 20 KB
    __shared__ float s_ea[4][CHUNK+1];
    __shared__ float asd[96], avd[288], hsl[96];

    float acc = 0.f;
    for (int c0 = rs; c0 < re; c0 += CHUNK){
        const int m = min(CHUNK, re - c0);
        __syncthreads();                          // protect LDS reuse across chunks
        if (t < m){
            float4 ea = eattr_s[c0 + t];
            s_ea[0][t] = ea.x; s_ea[1][t] = ea.y;
            s_ea[2][t] = ea.z; s_ea[3][t] = ea.w;
        }
        // w rows for the chunk are CONTIGUOUS: linear uint4 copy (m*24 vec4s)
        {
            const uint4* wsrc = reinterpret_cast<const uint4*>(w_s + (size_t)c0*WN);
            uint4* wdst = reinterpret_cast<uint4*>(s_w);
            for (int idx = t; idx < m*24; idx += 384) wdst[idx] = wsrc[idx];
        }
        // f_s rows: coalesced float4 row gathers (m*16 vec4s)
        for (int idx = t; idx < m*16; idx += 384){
            int row = idx >> 4, c = idx & 15;
            int src = esrc_s[c0 + row];
            *reinterpret_cast<float4*>(&s_f[row*160 + 4*c]) =
                *reinterpret_cast<const float4*>(&f_s[(size_t)src*64 + 4*c]);
        }
        // f_v rows (m*24 vec4s)
        for (int idx = t; idx < m*24; idx += 384){
            int row = idx/24, c = idx - row*24;
            int src = esrc_s[c0 + row];
            *reinterpret_cast<float4*>(&s_f[row*160 + 64 + 4*c]) =
                *reinterpret_cast<const float4*>(&f_v[(size_t)src*96 + 4*c]);
        }
        __syncthreads();

        // inner loop: pure LDS + VALU
        if (mode == 0){
            #pragma unroll 4
            for (int i = 0; i < m; ++i){
                float w = __half2float(s_w[i*WN + widx]);
                acc += w * s_f[i*160 + fidx] * s_ea[eac][i];
            }
        } else if (mode == 2){
            #pragma unroll 4
            for (int i = 0; i < m; ++i){
                float w = __half2float(s_w[i*WN + widx]);
                acc += w * s_f[i*160 + 64 + fidx] * s_ea[0][i];
            }
        } else {
            #pragma unroll 4
            for (int i = 0; i < m; ++i){
                float w = __half2float(s_w[i*WN + widx]);
                const float* p = &s_f[i*160 + 64 + fidx];
                float d = p[0]*s_ea[1][i] + p[1]*s_ea[2][i] + p[2]*s_ea[3][i];
                acc += w * d * INV_SQRT3;
            }
        }
    }
    acc *= isd[n];

    if (t < 64) asd[t] = acc;
    else if (t < 256) avd[t-64] = acc;
    else if (t < 352) avd[192 + (t-256)] = acc;
    else asd[64 + (t-352)] = acc;
    __syncthreads();

    const float a = attr[n];
    float ang = 0.f;
    #pragma unroll 8
    for (int k = 0; k < 96; ++k) ang += asd[k]*W3[k];
    ang *= 0.1f * a * INV_SQRT96;
    const float c_ = cosf(ang), s_ = sinf(ang);

    float hv = 0.f;
    if (t < OS){
        float d = 0.f;
        #pragma unroll 8
        for (int k = 0; k < 96; ++k) d += asd[k]*W2s[k*OS + t];
        float hsv = c_*sc_s[(size_t)n*OS + t] + s_*(d * a * INV_SQRT96);
        if (FINAL) out_s[(size_t)n*160 + t] = hsv;
        else       hsl[t] = hsv;
    }
    if (t >= 96 && t < 192){
        const int q2 = t - 96;
        const int ww = q2/3, c2 = q2 - 3*ww;
        float d = 0.f;
        #pragma unroll 8
        for (int k = 0; k < 96; ++k) d += avd[k*3 + c2]*W2v[k*32 + ww];
        hv = c_*sc_v[(size_t)n*96 + q2] + s_*(d * a * INV_SQRT96);
        if (FINAL) out_s[(size_t)n*160 + 64 + q2] = hv;
    }
    if (!FINAL){
        __syncthreads();
        if (t < 64) out_s[(size_t)n*64 + t] = siluf(hsl[t]);
        if (t >= 96 && t < 192){
            const int q2 = t - 96;
            const int ww = q2/3;
            float sg = 1.f / (1.f + __expf(-hsl[64 + ww]));
            out_v[(size_t)n*96 + q2] = sg * hv;
        }
    }
}

// ---------------- launch ----------------
extern "C" void kernel_launch(void* const* d_in, const int* in_sizes, int n_in,
                              void* d_out, int out_size, void* d_ws, size_t ws_size,
                              hipStream_t stream)
{
    const float* nf    = (const float*)d_in[0];
    const float* nattr = (const float*)d_in[1];
    const int*   esrc  = (const int*)  d_in[2];
    const int*   edst  = (const int*)  d_in[3];
    const float* eattr = (const float*)d_in[4];
    const float* escal = (const float*)d_in[5];
    const float* p1_sc_s = (const float*)d_in[6];
    const float* p1_sc_v = (const float*)d_in[7];
    const float* p1_l1_s = (const float*)d_in[8];
    const float* p1_l1_v = (const float*)d_in[9];
    const float* p1_fa   = (const float*)d_in[10];
    const float* p1_fb   = (const float*)d_in[11];
    const float* p1_l2_s = (const float*)d_in[12];
    const float* p1_l2_v = (const float*)d_in[13];
    const float* p1_l3   = (const float*)d_in[14];
    const float* p2_sc_s = (const float*)d_in[15];
    const float* p2_sc_v = (const float*)d_in[16];
    const float* p2_l1_s = (const float*)d_in[17];
    const float* p2_l1_v = (const float*)d_in[18];
    const float* p2_fa   = (const float*)d_in[19];
    const float* p2_fb   = (const float*)d_in[20];
    const float* p2_l2_s = (const float*)d_in[21];
    const float* p2_l2_v = (const float*)d_in[22];
    const float* p2_l3   = (const float*)d_in[23];

    const int N = in_sizes[1];
    const int E = in_sizes[2];

    // ---- workspace layout ----
    char* wsb = (char*)d_ws;
    __half* w_s     = (__half*)wsb;   wsb += (size_t)E*WN*2;
    float4* eattr_s = (float4*)wsb;   wsb += (size_t)E*16;
    __half* Wc1 = (__half*)wsb;       wsb += (size_t)(256*WPAD)*2;
    __half* Wc2 = (__half*)wsb;       wsb += (size_t)(256*WPAD)*2;
    float* fs   = (float*)wsb;        wsb += (size_t)N*64*4;
    float* fv   = (float*)wsb;        wsb += (size_t)N*96*4;
    float* scs  = (float*)wsb;        wsb += (size_t)N*96*4;
    float* scv  = (float*)wsb;        wsb += (size_t)N*96*4;
    float* gs   = (float*)wsb;        wsb += (size_t)N*64*4;
    float* gv   = (float*)wsb;        wsb += (size_t)N*96*4;
    float* isd  = (float*)wsb;        wsb += (size_t)N*4;
    int* cnt       = (int*)wsb;       wsb += (size_t)N*4;
    int* row_start = (int*)wsb;       wsb += (size_t)(N+1)*4;
    int* cursor    = (int*)wsb;       wsb += (size_t)N*4;
    int* perm      = (int*)wsb;       wsb += (size_t)E*4;
    int* esrc_s    = (int*)wsb;       wsb += (size_t)E*4;

    // ---- sort edges by dst + weight prep ----
    hipMemsetAsync(cnt, 0, (size_t)N*4, stream);
    hist_kernel<<<(E+255)/256, 256, 0, stream>>>(edst, cnt, E);
    scan_kernel<<<1, 1024, 0, stream>>>(cnt, row_start, cursor, N, E);
    scatter_kernel<<<(E+255)/256, 256, 0, stream>>>(edst, esrc, (const float4*)eattr,
                                                    cursor, perm, eattr_s, esrc_s, E);
    isd_kernel<<<(N+255)/256, 256, 0, stream>>>(cnt, isd, N);
    wprep<<<(256*WPAD+255)/256, 256, 0, stream>>>(p1_fa, p1_fb, p2_fa, p2_fb, Wc1, Wc2);

    const int gemm_grid = (E + 63)/64;

    // ---- conv1 ----
    {
        int tot = N*352;
        node_pre<96><<<(tot+255)/256, 256, 0, stream>>>(nf, 160, nf+64, 160, nattr,
            p1_l1_s, p1_sc_s, p1_l1_v, p1_sc_v, fs, scs, fv, scv, N);
    }
    mlp_gemm<<<gemm_grid, 256, 0, stream>>>(perm, escal, Wc1, w_s, E);
    agg_post<96, false><<<N, 384, 0, stream>>>(row_start, w_s, esrc_s, eattr_s,
        fs, fv, isd, nattr, scs, scv, p1_l2_s, p1_l2_v, p1_l3, gs, gv);

    // ---- conv2 ----
    {
        int tot = N*320;
        node_pre<64><<<(tot+255)/256, 256, 0, stream>>>(gs, 64, gv, 96, nattr,
            p2_l1_s, p2_sc_s, p2_l1_v, p2_sc_v, fs, scs, fv, scv, N);
    }
    mlp_gemm<<<gemm_grid, 256, 0, stream>>>(perm, escal, Wc2, w_s, E);
    agg_post<64, true><<<N, 384, 0, stream>>>(row_start, w_s, esrc_s, eattr_s,
        fs, fv, isd, nattr, scs, scv, p2_l2_s, p2_l2_v, p2_l3, (float*)d_out, nullptr);
}